// Round 1
// baseline (982.874 us; speedup 1.0000x reference)
//
#include <hip/hip_runtime.h>
#include <hip/hip_bf16.h>
#include <math.h>

#define NH 8
#define HD 16
#define EE 16
#define HH 128
#define TQ 256
#define TK 64

// ---------------- Kernel 1: QKV projection ----------------
// x: [B*S, E]; w*: [H, E]; b*: [H]
// Q,K,V out: [B*NH, S, HD]  (head-major for attention)
__global__ void qkv_proj(const float* __restrict__ x,
                         const float* __restrict__ wq, const float* __restrict__ bq,
                         const float* __restrict__ wk, const float* __restrict__ bk,
                         const float* __restrict__ wv, const float* __restrict__ bv,
                         float* __restrict__ Q, float* __restrict__ K, float* __restrict__ V,
                         int S) {
    int row = blockIdx.x;            // b*S + s
    int b = row / S, s = row - b * S;
    int h = threadIdx.x;             // 0..127
    __shared__ float xr[EE];
    if (h < EE) xr[h] = x[(size_t)row * EE + h];
    __syncthreads();
    float aq = bq[h], ak = bk[h], av = bv[h];
#pragma unroll
    for (int e = 0; e < EE; ++e) {
        float xe = xr[e];
        aq += xe * wq[h * EE + e];
        ak += xe * wk[h * EE + e];
        av += xe * wv[h * EE + e];
    }
    int head = h >> 4, d = h & 15;
    size_t idx = ((size_t)(b * NH + head) * S + s) * HD + d;
    Q[idx] = aq; K[idx] = ak; V[idx] = av;
}

// ---------------- Kernel 2: flash attention ----------------
// Q,K,V: [B*NH, S, HD]; O: [B*S, H] (interleaved heads for out_proj)
__global__ __launch_bounds__(TQ) void attn(const float* __restrict__ Q,
                                           const float* __restrict__ K,
                                           const float* __restrict__ V,
                                           float* __restrict__ O, int S) {
    int bh = blockIdx.y;             // 0..B*NH-1
    int q0 = blockIdx.x * TQ;
    int tid = threadIdx.x;
    int qi = q0 + tid;

    __shared__ float Ks[TK * HD];
    __shared__ float Vs[TK * HD];

    float q[HD];
    const float* qp = Q + ((size_t)bh * S + qi) * HD;
#pragma unroll
    for (int d = 0; d < HD; d += 4) {
        float4 t = *(const float4*)&qp[d];
        q[d]     = t.x * 0.25f;   // fold softmax scale 1/sqrt(16)
        q[d + 1] = t.y * 0.25f;
        q[d + 2] = t.z * 0.25f;
        q[d + 3] = t.w * 0.25f;
    }
    float m = -INFINITY, l = 0.f;
    float o[HD];
#pragma unroll
    for (int d = 0; d < HD; ++d) o[d] = 0.f;

    for (int k0 = 0; k0 < S; k0 += TK) {
        const float* kp = K + ((size_t)bh * S + k0) * HD;
        const float* vp = V + ((size_t)bh * S + k0) * HD;
        int i4 = tid * 4;            // TK*HD = 1024 floats, 256 thr * 4
        *(float4*)&Ks[i4] = *(const float4*)&kp[i4];
        *(float4*)&Vs[i4] = *(const float4*)&vp[i4];
        __syncthreads();

        float s[TK];
        float tm = -INFINITY;
#pragma unroll
        for (int j = 0; j < TK; ++j) {
            float acc = 0.f;
#pragma unroll
            for (int d = 0; d < HD; ++d) acc += q[d] * Ks[j * HD + d];
            s[j] = acc;
            tm = fmaxf(tm, acc);
        }
        float mn = fmaxf(m, tm);
        float alpha = __expf(m - mn);   // first tile: exp(-inf)=0
        l *= alpha;
#pragma unroll
        for (int d = 0; d < HD; ++d) o[d] *= alpha;
#pragma unroll
        for (int j = 0; j < TK; ++j) {
            float p = __expf(s[j] - mn);
            l += p;
#pragma unroll
            for (int d = 0; d < HD; ++d) o[d] += p * Vs[j * HD + d];
        }
        m = mn;
        __syncthreads();
    }

    int b = bh / NH, head = bh - b * NH;
    float inv_l = 1.f / l;
    float* op = O + ((size_t)(b * S + qi)) * HH + head * HD;
#pragma unroll
    for (int d = 0; d < HD; ++d) op[d] = o[d] * inv_l;
}

// ---------------- Kernel 3: output projection ----------------
// A: [rows, H]; wo: [E, H]; out: [rows, E]
__global__ void out_proj(const float* __restrict__ A, const float* __restrict__ wo,
                         const float* __restrict__ bo, float* __restrict__ out, int rows) {
    __shared__ float As[16][HH + 1];   // +1 pad: (r+h)%32 banks
    __shared__ float ws[EE][HH + 1];   // +1 pad: (e+h)%32 banks
    int r0 = blockIdx.x * 16;
    int tid = threadIdx.x;
#pragma unroll
    for (int i = 0; i < 8; ++i) {
        int idx = tid + i * 256;       // 0..2047
        ws[idx >> 7][idx & 127] = wo[idx];
        As[idx >> 7][idx & 127] = A[(size_t)r0 * HH + idx];
    }
    __syncthreads();
    int r = tid >> 4;       // 0..15
    int e = tid & 15;
    float acc = bo[e];
#pragma unroll
    for (int h = 0; h < HH; ++h) acc += As[r][h] * ws[e][h];
    out[(size_t)(r0 + r) * EE + e] = acc;
}

extern "C" void kernel_launch(void* const* d_in, const int* in_sizes, int n_in,
                              void* d_out, int out_size, void* d_ws, size_t ws_size,
                              hipStream_t stream) {
    const float* x  = (const float*)d_in[0];
    const float* wq = (const float*)d_in[1];
    const float* bq = (const float*)d_in[2];
    const float* wk = (const float*)d_in[3];
    const float* bk = (const float*)d_in[4];
    const float* wv = (const float*)d_in[5];
    const float* bv = (const float*)d_in[6];
    const float* wo = (const float*)d_in[7];
    const float* bo = (const float*)d_in[8];
    float* out = (float*)d_out;

    int rows = in_sizes[0] / EE;   // B*S
    int S = 4096;
    int B = rows / S;

    size_t n = (size_t)rows * HH;  // elements per Q/K/V/A buffer
    float* Q = (float*)d_ws;
    float* K = Q + n;
    float* V = K + n;
    float* A = V + n;

    qkv_proj<<<rows, 128, 0, stream>>>(x, wq, bq, wk, bk, wv, bv, Q, K, V, S);
    dim3 g2(S / TQ, B * NH);
    attn<<<g2, TQ, 0, stream>>>(Q, K, V, A, S);
    out_proj<<<rows / 16, 256, 0, stream>>>(A, wo, bo, out, rows);
}